// Round 1
// baseline (4890.088 us; speedup 1.0000x reference)
//
#include <hip/hip_runtime.h>
#include <hip/hip_bf16.h>
#include <stdint.h>

#define NB 8
#define NN 8192
#define NC 64
#define NS 2048
#define NK 32
#define NCOL (NB*NS*NK)   // 524288 columns (b,s,n)

// ---------- bf16 helpers (RNE) ----------
__device__ __forceinline__ unsigned short f2bf(float x) {
    union { float f; unsigned u; } c; c.f = x;
    unsigned r = c.u + 0x7fffu + ((c.u >> 16) & 1u);
    return (unsigned short)(r >> 16);
}
__device__ __forceinline__ float bf2f(unsigned v16) {
    union { float f; unsigned u; } c; c.u = v16 << 16;
    return c.f;
}

// ============================================================================
// 1) Furthest point sampling: one block per batch, 1024 threads, 8 pts/thread.
//    Must match fp32 reference bit-exactly: no FMA contraction, (dx2+dy2)+dz2
//    order, argmax tie-break = smallest index.
// ============================================================================
__global__ __launch_bounds__(1024) void fps_kernel(const float* __restrict__ xyz,
    float* __restrict__ new_xyz, float* __restrict__ out_newxyz)
{
#pragma clang fp contract(off)
    const int b = blockIdx.x;
    const int tid = threadIdx.x;
    const float* xb = xyz + (size_t)b * NN * 3;
    float px[8], py[8], pz[8], dmin[8];
#pragma unroll
    for (int j = 0; j < 8; ++j) {
        int p = j * 1024 + tid;
        px[j] = xb[p*3+0]; py[j] = xb[p*3+1]; pz[j] = xb[p*3+2];
        dmin[j] = 1e10f;
    }
    __shared__ float s_val[16];
    __shared__ int   s_idx[16];
    __shared__ float s_pt[3];
    float lx = xb[0], ly = xb[1], lz = xb[2];
    if (tid == 0) {  // selection 0 = point 0
        float* nw = new_xyz + (size_t)b * NS * 3;
        float* ow = out_newxyz + (size_t)b * NS * 3;
        nw[0] = lx; nw[1] = ly; nw[2] = lz;
        ow[0] = lx; ow[1] = ly; ow[2] = lz;
    }
    const int lane = tid & 63, wv = tid >> 6;
    for (int i = 1; i < NS; ++i) {
        float best = -1.0f; int bestidx = 0;
#pragma unroll
        for (int j = 0; j < 8; ++j) {
            float dx = px[j] - lx;
            float dy = py[j] - ly;
            float dz = pz[j] - lz;
            float d = (dx*dx + dy*dy) + dz*dz;   // contract(off): exact order
            float dm = fminf(dmin[j], d);
            dmin[j] = dm;
            // strict >: within a thread j ascending => point idx ascending,
            // keeps the earliest maximal index
            if (dm > best) { best = dm; bestidx = j * 1024 + tid; }
        }
        // wave butterfly argmax (tie -> smaller index)
#pragma unroll
        for (int off = 32; off >= 1; off >>= 1) {
            float ov = __shfl_xor(best, off);
            int   oi = __shfl_xor(bestidx, off);
            if (ov > best || (ov == best && oi < bestidx)) { best = ov; bestidx = oi; }
        }
        if (lane == 0) { s_val[wv] = best; s_idx[wv] = bestidx; }
        __syncthreads();
        // every wave redundantly reduces the 16 wave winners
        float v = (lane < 16) ? s_val[lane] : -1.0f;
        int  ix = (lane < 16) ? s_idx[lane] : 0x7fffffff;
#pragma unroll
        for (int off = 8; off >= 1; off >>= 1) {
            float ov = __shfl_xor(v, off);
            int   oi = __shfl_xor(ix, off);
            if (ov > v || (ov == v && oi < ix)) { v = ov; ix = oi; }
        }
        ix = __shfl(ix, 0);
        if ((ix & 1023) == tid) {         // owner thread broadcasts coords
            int j = ix >> 10;
            s_pt[0] = px[j]; s_pt[1] = py[j]; s_pt[2] = pz[j];
            float* nw = new_xyz + ((size_t)b * NS + i) * 3;
            float* ow = out_newxyz + ((size_t)b * NS + i) * 3;
            nw[0] = px[j]; nw[1] = py[j]; nw[2] = pz[j];
            ow[0] = px[j]; ow[1] = py[j]; ow[2] = pz[j];
        }
        __syncthreads();
        lx = s_pt[0]; ly = s_pt[1]; lz = s_pt[2];
    }
}

// ============================================================================
// 2) Transpose features (B,C,N) -> (B,N,C) for contiguous per-point gathers.
// ============================================================================
__global__ __launch_bounds__(256) void transpose_kernel(const float* __restrict__ f,
    float* __restrict__ ft)
{
    __shared__ float tile[64][65];
    int b = blockIdx.y;
    int p0 = blockIdx.x * 64;
    for (int k = threadIdx.x; k < 64*64; k += 256) {
        int c = k >> 6, p = k & 63;
        tile[c][p] = f[((size_t)b * NC + c) * NN + p0 + p];
    }
    __syncthreads();
    for (int k = threadIdx.x; k < 64*64; k += 256) {
        int p = k >> 6, c = k & 63;
        ft[((size_t)b * NN + p0 + p) * NC + c] = tile[c][p];
    }
}

// ============================================================================
// 3) Ball query: one wave per (b,s) query. First 32 smallest in-ball indices,
//    pad with first. r2 must be float(0.2*0.2) = 0.0399999991 (not 0.2f*0.2f).
// ============================================================================
__global__ __launch_bounds__(256) void ballquery_kernel(const float* __restrict__ xyz,
    const float* __restrict__ new_xyz, int* __restrict__ idx)
{
#pragma clang fp contract(off)
    const int q = blockIdx.x * 4 + (threadIdx.x >> 6);
    const int lane = threadIdx.x & 63;
    const int b = q >> 11;
    const float r2 = (float)(0.2 * 0.2);
    const float* xb = xyz + (size_t)b * NN * 3;
    const float* nx = new_xyz + (size_t)q * 3;
    float qx = nx[0], qy = nx[1], qz = nx[2];
    int cnt = 0, first = -1;
    int* out = idx + (size_t)q * NK;
    for (int base = 0; base < NN; base += 64) {
        int p = base + lane;
        float x = xb[p*3+0], y = xb[p*3+1], z = xb[p*3+2];
        float dx = qx - x, dy = qy - y, dz = qz - z;
        float d2 = (dx*dx + dy*dy) + dz*dz;
        bool in = d2 < r2;
        unsigned long long m = __ballot(in);
        if (m) {
            if (first < 0) first = base + __builtin_ctzll(m);
            if (in) {
                int rank = cnt + __popcll(m & ((1ull << lane) - 1ull));
                if (rank < NK) out[rank] = p;
            }
            cnt += __popcll(m);
            if (cnt >= NK) break;
        }
    }
    for (int k = cnt + lane; k < NK; k += 64) out[k] = first;  // cnt>=1 always
}

// ============================================================================
// 4) Layer 1: h1 = W1(64x67) @ g, one thread per column (b,s,n). h1 bf16.
// ============================================================================
__global__ __launch_bounds__(256) void layer1_kernel(const float* __restrict__ xyz,
    const float* __restrict__ new_xyz, const int* __restrict__ idx,
    const float* __restrict__ ft, const float* __restrict__ W1,
    unsigned short* __restrict__ h1)
{
    const int col = blockIdx.x * 256 + threadIdx.x;
    const int b = col >> 16;
    const int s = (col >> 5) & 2047;
    const int p = idx[col];
    float g[67];
    {
        const float* nx = new_xyz + ((size_t)(b * NS + s)) * 3;
        const float* xp = xyz + ((size_t)(b * NN + p)) * 3;
        g[0] = xp[0] - nx[0]; g[1] = xp[1] - nx[1]; g[2] = xp[2] - nx[2];
    }
    const float4* fp = (const float4*)(ft + ((size_t)(b * NN + p)) * NC);
#pragma unroll
    for (int c4 = 0; c4 < 16; ++c4) {
        float4 v = fp[c4];
        g[3 + 4*c4 + 0] = v.x; g[3 + 4*c4 + 1] = v.y;
        g[3 + 4*c4 + 2] = v.z; g[3 + 4*c4 + 3] = v.w;
    }
    float h[64];
#pragma unroll 4
    for (int o = 0; o < 64; ++o) {
        const float* w = W1 + o * 67;
        float a = 0.f;
#pragma unroll
        for (int c = 0; c < 67; ++c) a = fmaf(w[c], g[c], a);
        h[o] = a;
    }
    uint4* dst = (uint4*)(h1 + (size_t)col * 64);
#pragma unroll
    for (int k = 0; k < 8; ++k) {
        uint4 v;
        v.x = (unsigned)f2bf(h[8*k+0]) | ((unsigned)f2bf(h[8*k+1]) << 16);
        v.y = (unsigned)f2bf(h[8*k+2]) | ((unsigned)f2bf(h[8*k+3]) << 16);
        v.z = (unsigned)f2bf(h[8*k+4]) | ((unsigned)f2bf(h[8*k+5]) << 16);
        v.w = (unsigned)f2bf(h[8*k+6]) | ((unsigned)f2bf(h[8*k+7]) << 16);
        dst[k] = v;
    }
}

// ============================================================================
// 5) Stats pass over a bf16 [col][64] tensor: per-channel sum / sumsq.
// ============================================================================
__global__ __launch_bounds__(256) void stats_kernel(const unsigned short* __restrict__ h,
    float* __restrict__ sums)
{
    __shared__ float ls[64], lq[64];
    const int tid = threadIdx.x;
    if (tid < 64) { ls[tid] = 0.f; lq[tid] = 0.f; }
    __syncthreads();
    float s[8] = {0,0,0,0,0,0,0,0}, q[8] = {0,0,0,0,0,0,0,0};
    const int gt = blockIdx.x * 256 + tid;
    const int G = gridDim.x * 256;            // multiple of 8 -> channel phase fixed
    const uint4* src = (const uint4*)h;
    const int nvec = NCOL * 8;                 // uint4s (8 bf16 each)
    for (int i = gt; i < nvec; i += G) {
        uint4 v = src[i];
        float f0 = bf2f(v.x & 0xffffu), f1 = bf2f(v.x >> 16);
        float f2 = bf2f(v.y & 0xffffu), f3 = bf2f(v.y >> 16);
        float f4 = bf2f(v.z & 0xffffu), f5 = bf2f(v.z >> 16);
        float f6 = bf2f(v.w & 0xffffu), f7 = bf2f(v.w >> 16);
        s[0] += f0; q[0] = fmaf(f0, f0, q[0]);
        s[1] += f1; q[1] = fmaf(f1, f1, q[1]);
        s[2] += f2; q[2] = fmaf(f2, f2, q[2]);
        s[3] += f3; q[3] = fmaf(f3, f3, q[3]);
        s[4] += f4; q[4] = fmaf(f4, f4, q[4]);
        s[5] += f5; q[5] = fmaf(f5, f5, q[5]);
        s[6] += f6; q[6] = fmaf(f6, f6, q[6]);
        s[7] += f7; q[7] = fmaf(f7, f7, q[7]);
    }
    const int obase = (tid & 7) * 8;
#pragma unroll
    for (int j = 0; j < 8; ++j) {
        atomicAdd(&ls[obase + j], s[j]);
        atomicAdd(&lq[obase + j], q[j]);
    }
    __syncthreads();
    if (tid < 64) {
        atomicAdd(&sums[tid*2+0], ls[tid]);
        atomicAdd(&sums[tid*2+1], lq[tid]);
    }
}

// ============================================================================
// 6) Finalize BN params: a = gamma/sqrt(var+eps), c = beta - mu*a.
// ============================================================================
__global__ void finalize_kernel(const float* __restrict__ sums,
    const float* __restrict__ gamma, const float* __restrict__ beta,
    float* __restrict__ ab, int nch)
{
    int c = threadIdx.x;
    if (c < nch) {
        const float invM = 1.0f / 524288.0f;
        float mu = sums[c*2] * invM;
        float var = sums[c*2+1] * invM - mu * mu;
        float a = gamma[c] / sqrtf(var + 1e-5f);
        ab[c*2+0] = a;
        ab[c*2+1] = fmaf(-mu, a, beta[c]);
    }
}

// ============================================================================
// 7) Layer 2: g2 = relu(BN1(h1)); h2 = W2(64x64) @ g2. h2 bf16.
// ============================================================================
__global__ __launch_bounds__(256) void layer2_kernel(const unsigned short* __restrict__ h1,
    const float* __restrict__ ab1, const float* __restrict__ W2,
    unsigned short* __restrict__ h2)
{
    const int col = blockIdx.x * 256 + threadIdx.x;
    const uint4* src = (const uint4*)(h1 + (size_t)col * 64);
    float g[64];
#pragma unroll
    for (int k = 0; k < 8; ++k) {
        uint4 v = src[k];
        g[8*k+0] = bf2f(v.x & 0xffffu); g[8*k+1] = bf2f(v.x >> 16);
        g[8*k+2] = bf2f(v.y & 0xffffu); g[8*k+3] = bf2f(v.y >> 16);
        g[8*k+4] = bf2f(v.z & 0xffffu); g[8*k+5] = bf2f(v.z >> 16);
        g[8*k+6] = bf2f(v.w & 0xffffu); g[8*k+7] = bf2f(v.w >> 16);
    }
#pragma unroll
    for (int c = 0; c < 64; ++c)
        g[c] = fmaxf(fmaf(ab1[c*2], g[c], ab1[c*2+1]), 0.f);
    float h[64];
#pragma unroll 4
    for (int o = 0; o < 64; ++o) {
        const float* w = W2 + (o << 6);
        float a = 0.f;
#pragma unroll
        for (int c = 0; c < 64; ++c) a = fmaf(w[c], g[c], a);
        h[o] = a;
    }
    uint4* dst = (uint4*)(h2 + (size_t)col * 64);
#pragma unroll
    for (int k = 0; k < 8; ++k) {
        uint4 v;
        v.x = (unsigned)f2bf(h[8*k+0]) | ((unsigned)f2bf(h[8*k+1]) << 16);
        v.y = (unsigned)f2bf(h[8*k+2]) | ((unsigned)f2bf(h[8*k+3]) << 16);
        v.z = (unsigned)f2bf(h[8*k+4]) | ((unsigned)f2bf(h[8*k+5]) << 16);
        v.w = (unsigned)f2bf(h[8*k+6]) | ((unsigned)f2bf(h[8*k+7]) << 16);
        dst[k] = v;
    }
}

// ============================================================================
// 8) Layer 3: g3 = relu(BN2(h2)); h3 = W3(128x64) @ g3. No h3 materialization:
//    per (b,s) group (32 lanes) reduce max/min over n, and sum/sumsq for stats.
// ============================================================================
__global__ __launch_bounds__(256) void layer3_kernel(const unsigned short* __restrict__ h2,
    const float* __restrict__ ab2, const float* __restrict__ W3,
    float* __restrict__ hmax, float* __restrict__ hmin, float* __restrict__ sums3)
{
    __shared__ float ls[128], lq[128];
    const int tid = threadIdx.x;
    if (tid < 128) { ls[tid] = 0.f; lq[tid] = 0.f; }
    __syncthreads();
    const int col = blockIdx.x * 256 + tid;
    const int q = col >> 5;            // group (b*2048+s); lanes 0-31 / 32-63
    const uint4* src = (const uint4*)(h2 + (size_t)col * 64);
    float g[64];
#pragma unroll
    for (int k = 0; k < 8; ++k) {
        uint4 v = src[k];
        g[8*k+0] = bf2f(v.x & 0xffffu); g[8*k+1] = bf2f(v.x >> 16);
        g[8*k+2] = bf2f(v.y & 0xffffu); g[8*k+3] = bf2f(v.y >> 16);
        g[8*k+4] = bf2f(v.z & 0xffffu); g[8*k+5] = bf2f(v.z >> 16);
        g[8*k+6] = bf2f(v.w & 0xffffu); g[8*k+7] = bf2f(v.w >> 16);
    }
#pragma unroll
    for (int c = 0; c < 64; ++c)
        g[c] = fmaxf(fmaf(ab2[c*2], g[c], ab2[c*2+1]), 0.f);
#pragma unroll 2
    for (int o = 0; o < 128; ++o) {
        const float* w = W3 + (o << 6);
        float acc = 0.f;
#pragma unroll
        for (int c = 0; c < 64; ++c) acc = fmaf(w[c], g[c], acc);
        float sm = acc, sq = acc*acc, mx = acc, mn = acc;
#pragma unroll
        for (int off = 16; off >= 1; off >>= 1) {  // xor<32 stays in 32-lane half
            sm += __shfl_xor(sm, off);
            sq += __shfl_xor(sq, off);
            mx = fmaxf(mx, __shfl_xor(mx, off));
            mn = fminf(mn, __shfl_xor(mn, off));
        }
        if ((tid & 31) == 0) {
            hmax[(size_t)o * 16384 + q] = mx;
            hmin[(size_t)o * 16384 + q] = mn;
            atomicAdd(&ls[o], sm);
            atomicAdd(&lq[o], sq);
        }
    }
    __syncthreads();
    if (tid < 128) {
        atomicAdd(&sums3[tid*2+0], ls[tid]);
        atomicAdd(&sums3[tid*2+1], lq[tid]);
    }
}

// ============================================================================
// 9) Final: feats[b,o,s] = relu(a3*(a3>=0 ? max : min) + c3)
// ============================================================================
__global__ __launch_bounds__(256) void final_kernel(const float* __restrict__ hmax,
    const float* __restrict__ hmin, const float* __restrict__ ab3,
    float* __restrict__ out)
{
    const int t = blockIdx.x * 256 + threadIdx.x;   // (b,o,s), s fastest
    const int s = t & 2047;
    const int o = (t >> 11) & 127;
    const int b = t >> 18;
    const int q = (b << 11) + s;
    float a = ab3[o*2], c = ab3[o*2+1];
    float h = (a >= 0.f) ? hmax[(size_t)o * 16384 + q] : hmin[(size_t)o * 16384 + q];
    out[t] = fmaxf(fmaf(a, h, c), 0.f);
}

// ============================================================================
extern "C" void kernel_launch(void* const* d_in, const int* in_sizes, int n_in,
                              void* d_out, int out_size, void* d_ws, size_t ws_size,
                              hipStream_t stream) {
    (void)in_sizes; (void)n_in; (void)out_size; (void)ws_size;
    const float* xyz      = (const float*)d_in[0];
    const float* features = (const float*)d_in[1];
    const float* W1 = (const float*)d_in[2];
    const float* g1 = (const float*)d_in[3];
    const float* b1 = (const float*)d_in[4];
    const float* W2 = (const float*)d_in[5];
    const float* g2 = (const float*)d_in[6];
    const float* b2 = (const float*)d_in[7];
    const float* W3 = (const float*)d_in[8];
    const float* g3 = (const float*)d_in[9];
    const float* b3 = (const float*)d_in[10];

    char* ws = (char*)d_ws;
    float*          new_xyz = (float*)(ws + 0);                  // 196608 B
    int*            idx     = (int*)(ws + 196608);               // 2097152 B
    float*          ft      = (float*)(ws + 2293760);            // 16777216 B
    unsigned short* h1      = (unsigned short*)(ws + 19070976);  // 67108864 B
    unsigned short* h2      = (unsigned short*)(ws + 86179840);  // 67108864 B
    float*          hmax    = (float*)(ws + 153288704);          // 8388608 B
    float*          hmin    = (float*)(ws + 161677312);          // 8388608 B
    float*          sums    = (float*)(ws + 170065920);          // 2048 B (zeroed)
    float*          ab      = (float*)(ws + 170067968);          // 2048 B
    float* sums1 = sums;        float* ab1 = ab;
    float* sums2 = sums + 128;  float* ab2 = ab + 128;
    float* sums3 = sums + 256;  float* ab3 = ab + 256;

    float* out_newxyz = (float*)d_out;            // B*NS*3 = 49152 floats
    float* out_feats  = (float*)d_out + 49152;    // B*128*NS floats

    hipMemsetAsync(sums, 0, 2048, stream);

    fps_kernel<<<NB, 1024, 0, stream>>>(xyz, new_xyz, out_newxyz);
    transpose_kernel<<<dim3(NN/64, NB), 256, 0, stream>>>(features, ft);
    ballquery_kernel<<<(NB*NS)/4, 256, 0, stream>>>(xyz, new_xyz, idx);
    layer1_kernel<<<NCOL/256, 256, 0, stream>>>(xyz, new_xyz, idx, ft, W1, h1);
    stats_kernel<<<1024, 256, 0, stream>>>(h1, sums1);
    finalize_kernel<<<1, 128, 0, stream>>>(sums1, g1, b1, ab1, 64);
    layer2_kernel<<<NCOL/256, 256, 0, stream>>>(h1, ab1, W2, h2);
    stats_kernel<<<1024, 256, 0, stream>>>(h2, sums2);
    finalize_kernel<<<1, 128, 0, stream>>>(sums2, g2, b2, ab2, 64);
    layer3_kernel<<<NCOL/256, 256, 0, stream>>>(h2, ab2, W3, hmax, hmin, sums3);
    finalize_kernel<<<1, 128, 0, stream>>>(sums3, g3, b3, ab3, 128);
    final_kernel<<<(NB*128*NS)/256, 256, 0, stream>>>(hmax, hmin, ab3, out_feats);
}

// Round 2
// 3334.175 us; speedup vs baseline: 1.4667x; 1.4667x over previous
//
#include <hip/hip_runtime.h>
#include <hip/hip_bf16.h>
#include <stdint.h>

#define NB 8
#define NN 8192
#define NC 64
#define NS 2048
#define NK 32
#define NCOL (NB*NS*NK)   // 524288 columns (b,s,n)

// ---------- bf16 helpers (RNE) ----------
__device__ __forceinline__ unsigned short f2bf(float x) {
    union { float f; unsigned u; } c; c.f = x;
    unsigned r = c.u + 0x7fffu + ((c.u >> 16) & 1u);
    return (unsigned short)(r >> 16);
}
__device__ __forceinline__ float bf2f(unsigned v16) {
    union { float f; unsigned u; } c; c.u = v16 << 16;
    return c.f;
}

// ============================================================================
// 1) Furthest point sampling: one block per batch, 512 threads, 16 pts/thread.
//    Exact fp32 match: contract(off), (dx2+dy2)+dz2 order, argmax tie = first.
//    Single barrier per iteration:
//      - xyz staged in LDS -> winner coords readable by ALL threads by index
//        (no owner-broadcast + second barrier)
//      - (value, ~index) packed in u64 -> umax == argmax w/ smallest-idx tie
//      - per-wave winner slots double-buffered by iteration parity
// ============================================================================
__global__ __launch_bounds__(512) void fps_kernel(const float* __restrict__ xyz,
    float* __restrict__ new_xyz, float* __restrict__ out_newxyz)
{
#pragma clang fp contract(off)
    const int b = blockIdx.x;
    const int tid = threadIdx.x;
    const float* xb = xyz + (size_t)b * NN * 3;
    __shared__ float sx[NN], sy[NN], sz[NN];            // 96 KB
    __shared__ unsigned long long s_key[2][8];
    float px[16], py[16], pz[16], dmin[16];
#pragma unroll
    for (int j = 0; j < 16; ++j) {
        int p = j * 512 + tid;                           // j-major: idx asc in j
        float x = xb[p*3+0], y = xb[p*3+1], z = xb[p*3+2];
        px[j] = x; py[j] = y; pz[j] = z; dmin[j] = 1e10f;
        sx[p] = x; sy[p] = y; sz[p] = z;
    }
    float lx = xb[0], ly = xb[1], lz = xb[2];            // selection 0 = point 0
    if (tid == 0) {
        float* nw = new_xyz + (size_t)b * NS * 3;
        float* ow = out_newxyz + (size_t)b * NS * 3;
        nw[0] = lx; nw[1] = ly; nw[2] = lz;
        ow[0] = lx; ow[1] = ly; ow[2] = lz;
    }
    const int lane = tid & 63, wv = tid >> 6;
    for (int i = 1; i < NS; ++i) {
        float best = -1.0f; int bestj = 0;
#pragma unroll
        for (int j = 0; j < 16; ++j) {
            float dx = px[j] - lx;
            float dy = py[j] - ly;
            float dz = pz[j] - lz;
            float d = (dx*dx + dy*dy) + dz*dz;           // contract(off): exact
            float dm = fminf(dmin[j], d);
            dmin[j] = dm;
            if (dm > best) { best = dm; bestj = j; }     // strict >: first max
        }
        // pack: high32 = float bits (monotone, d>=0), low32 = ~pointidx
        // umax => max value, tie -> smallest point index
        unsigned long long key =
            ((unsigned long long)__float_as_uint(best) << 32)
            | (unsigned)(~(bestj * 512 + tid));
#pragma unroll
        for (int off = 32; off >= 1; off >>= 1) {
            unsigned long long o = __shfl_xor(key, off);
            if (o > key) key = o;
        }
        if (lane == 0) s_key[i & 1][wv] = key;
        __syncthreads();                                  // the ONLY barrier
        unsigned long long k2 = s_key[i & 1][lane & 7];
#pragma unroll
        for (int off = 4; off >= 1; off >>= 1) {
            unsigned long long o = __shfl_xor(k2, off);
            if (o > k2) k2 = o;
        }
        const int ix = (int)(~(unsigned)k2);
        lx = sx[ix]; ly = sy[ix]; lz = sz[ix];            // LDS broadcast read
        if (tid == 0) {
            float* nw = new_xyz + ((size_t)b * NS + i) * 3;
            float* ow = out_newxyz + ((size_t)b * NS + i) * 3;
            nw[0] = lx; nw[1] = ly; nw[2] = lz;
            ow[0] = lx; ow[1] = ly; ow[2] = lz;
        }
    }
}

// ============================================================================
// 2) Transpose features (B,C,N) -> (B,N,C) for contiguous per-point gathers.
// ============================================================================
__global__ __launch_bounds__(256) void transpose_kernel(const float* __restrict__ f,
    float* __restrict__ ft)
{
    __shared__ float tile[64][65];
    int b = blockIdx.y;
    int p0 = blockIdx.x * 64;
    for (int k = threadIdx.x; k < 64*64; k += 256) {
        int c = k >> 6, p = k & 63;
        tile[c][p] = f[((size_t)b * NC + c) * NN + p0 + p];
    }
    __syncthreads();
    for (int k = threadIdx.x; k < 64*64; k += 256) {
        int p = k >> 6, c = k & 63;
        ft[((size_t)b * NN + p0 + p) * NC + c] = tile[c][p];
    }
}

// ============================================================================
// 3) Ball query: one wave per (b,s) query. First 32 smallest in-ball indices,
//    pad with first. r2 must be float(0.2*0.2) = 0.0399999991 (not 0.2f*0.2f).
// ============================================================================
__global__ __launch_bounds__(256) void ballquery_kernel(const float* __restrict__ xyz,
    const float* __restrict__ new_xyz, int* __restrict__ idx)
{
#pragma clang fp contract(off)
    const int q = blockIdx.x * 4 + (threadIdx.x >> 6);
    const int lane = threadIdx.x & 63;
    const int b = q >> 11;
    const float r2 = (float)(0.2 * 0.2);
    const float* xb = xyz + (size_t)b * NN * 3;
    const float* nx = new_xyz + (size_t)q * 3;
    float qx = nx[0], qy = nx[1], qz = nx[2];
    int cnt = 0, first = -1;
    int* out = idx + (size_t)q * NK;
    for (int base = 0; base < NN; base += 64) {
        int p = base + lane;
        float x = xb[p*3+0], y = xb[p*3+1], z = xb[p*3+2];
        float dx = qx - x, dy = qy - y, dz = qz - z;
        float d2 = (dx*dx + dy*dy) + dz*dz;
        bool in = d2 < r2;
        unsigned long long m = __ballot(in);
        if (m) {
            if (first < 0) first = base + __builtin_ctzll(m);
            if (in) {
                int rank = cnt + __popcll(m & ((1ull << lane) - 1ull));
                if (rank < NK) out[rank] = p;
            }
            cnt += __popcll(m);
            if (cnt >= NK) break;
        }
    }
    for (int k = cnt + lane; k < NK; k += 64) out[k] = first;  // cnt>=1 always
}

// ============================================================================
// 4) Layer 1: h1 = W1(64x67) @ g, one thread per column (b,s,n). h1 bf16.
// ============================================================================
__global__ __launch_bounds__(256) void layer1_kernel(const float* __restrict__ xyz,
    const float* __restrict__ new_xyz, const int* __restrict__ idx,
    const float* __restrict__ ft, const float* __restrict__ W1,
    unsigned short* __restrict__ h1)
{
    const int col = blockIdx.x * 256 + threadIdx.x;
    const int b = col >> 16;
    const int s = (col >> 5) & 2047;
    const int p = idx[col];
    float g[67];
    {
        const float* nx = new_xyz + ((size_t)(b * NS + s)) * 3;
        const float* xp = xyz + ((size_t)(b * NN + p)) * 3;
        g[0] = xp[0] - nx[0]; g[1] = xp[1] - nx[1]; g[2] = xp[2] - nx[2];
    }
    const float4* fp = (const float4*)(ft + ((size_t)(b * NN + p)) * NC);
#pragma unroll
    for (int c4 = 0; c4 < 16; ++c4) {
        float4 v = fp[c4];
        g[3 + 4*c4 + 0] = v.x; g[3 + 4*c4 + 1] = v.y;
        g[3 + 4*c4 + 2] = v.z; g[3 + 4*c4 + 3] = v.w;
    }
    float h[64];
#pragma unroll 4
    for (int o = 0; o < 64; ++o) {
        const float* w = W1 + o * 67;
        float a = 0.f;
#pragma unroll
        for (int c = 0; c < 67; ++c) a = fmaf(w[c], g[c], a);
        h[o] = a;
    }
    uint4* dst = (uint4*)(h1 + (size_t)col * 64);
#pragma unroll
    for (int k = 0; k < 8; ++k) {
        uint4 v;
        v.x = (unsigned)f2bf(h[8*k+0]) | ((unsigned)f2bf(h[8*k+1]) << 16);
        v.y = (unsigned)f2bf(h[8*k+2]) | ((unsigned)f2bf(h[8*k+3]) << 16);
        v.z = (unsigned)f2bf(h[8*k+4]) | ((unsigned)f2bf(h[8*k+5]) << 16);
        v.w = (unsigned)f2bf(h[8*k+6]) | ((unsigned)f2bf(h[8*k+7]) << 16);
        dst[k] = v;
    }
}

// ============================================================================
// 5) Stats pass over a bf16 [col][64] tensor: per-channel sum / sumsq.
// ============================================================================
__global__ __launch_bounds__(256) void stats_kernel(const unsigned short* __restrict__ h,
    float* __restrict__ sums)
{
    __shared__ float ls[64], lq[64];
    const int tid = threadIdx.x;
    if (tid < 64) { ls[tid] = 0.f; lq[tid] = 0.f; }
    __syncthreads();
    float s[8] = {0,0,0,0,0,0,0,0}, q[8] = {0,0,0,0,0,0,0,0};
    const int gt = blockIdx.x * 256 + tid;
    const int G = gridDim.x * 256;            // multiple of 8 -> channel phase fixed
    const uint4* src = (const uint4*)h;
    const int nvec = NCOL * 8;                 // uint4s (8 bf16 each)
    for (int i = gt; i < nvec; i += G) {
        uint4 v = src[i];
        float f0 = bf2f(v.x & 0xffffu), f1 = bf2f(v.x >> 16);
        float f2 = bf2f(v.y & 0xffffu), f3 = bf2f(v.y >> 16);
        float f4 = bf2f(v.z & 0xffffu), f5 = bf2f(v.z >> 16);
        float f6 = bf2f(v.w & 0xffffu), f7 = bf2f(v.w >> 16);
        s[0] += f0; q[0] = fmaf(f0, f0, q[0]);
        s[1] += f1; q[1] = fmaf(f1, f1, q[1]);
        s[2] += f2; q[2] = fmaf(f2, f2, q[2]);
        s[3] += f3; q[3] = fmaf(f3, f3, q[3]);
        s[4] += f4; q[4] = fmaf(f4, f4, q[4]);
        s[5] += f5; q[5] = fmaf(f5, f5, q[5]);
        s[6] += f6; q[6] = fmaf(f6, f6, q[6]);
        s[7] += f7; q[7] = fmaf(f7, f7, q[7]);
    }
    const int obase = (tid & 7) * 8;
#pragma unroll
    for (int j = 0; j < 8; ++j) {
        atomicAdd(&ls[obase + j], s[j]);
        atomicAdd(&lq[obase + j], q[j]);
    }
    __syncthreads();
    if (tid < 64) {
        atomicAdd(&sums[tid*2+0], ls[tid]);
        atomicAdd(&sums[tid*2+1], lq[tid]);
    }
}

// ============================================================================
// 6) Finalize BN params: a = gamma/sqrt(var+eps), c = beta - mu*a.
// ============================================================================
__global__ void finalize_kernel(const float* __restrict__ sums,
    const float* __restrict__ gamma, const float* __restrict__ beta,
    float* __restrict__ ab, int nch)
{
    int c = threadIdx.x;
    if (c < nch) {
        const float invM = 1.0f / 524288.0f;
        float mu = sums[c*2] * invM;
        float var = sums[c*2+1] * invM - mu * mu;
        float a = gamma[c] / sqrtf(var + 1e-5f);
        ab[c*2+0] = a;
        ab[c*2+1] = fmaf(-mu, a, beta[c]);
    }
}

// ============================================================================
// 7) Layer 2: g2 = relu(BN1(h1)); h2 = W2(64x64) @ g2. h2 bf16.
// ============================================================================
__global__ __launch_bounds__(256) void layer2_kernel(const unsigned short* __restrict__ h1,
    const float* __restrict__ ab1, const float* __restrict__ W2,
    unsigned short* __restrict__ h2)
{
    const int col = blockIdx.x * 256 + threadIdx.x;
    const uint4* src = (const uint4*)(h1 + (size_t)col * 64);
    float g[64];
#pragma unroll
    for (int k = 0; k < 8; ++k) {
        uint4 v = src[k];
        g[8*k+0] = bf2f(v.x & 0xffffu); g[8*k+1] = bf2f(v.x >> 16);
        g[8*k+2] = bf2f(v.y & 0xffffu); g[8*k+3] = bf2f(v.y >> 16);
        g[8*k+4] = bf2f(v.z & 0xffffu); g[8*k+5] = bf2f(v.z >> 16);
        g[8*k+6] = bf2f(v.w & 0xffffu); g[8*k+7] = bf2f(v.w >> 16);
    }
#pragma unroll
    for (int c = 0; c < 64; ++c)
        g[c] = fmaxf(fmaf(ab1[c*2], g[c], ab1[c*2+1]), 0.f);
    float h[64];
#pragma unroll 4
    for (int o = 0; o < 64; ++o) {
        const float* w = W2 + (o << 6);
        float a = 0.f;
#pragma unroll
        for (int c = 0; c < 64; ++c) a = fmaf(w[c], g[c], a);
        h[o] = a;
    }
    uint4* dst = (uint4*)(h2 + (size_t)col * 64);
#pragma unroll
    for (int k = 0; k < 8; ++k) {
        uint4 v;
        v.x = (unsigned)f2bf(h[8*k+0]) | ((unsigned)f2bf(h[8*k+1]) << 16);
        v.y = (unsigned)f2bf(h[8*k+2]) | ((unsigned)f2bf(h[8*k+3]) << 16);
        v.z = (unsigned)f2bf(h[8*k+4]) | ((unsigned)f2bf(h[8*k+5]) << 16);
        v.w = (unsigned)f2bf(h[8*k+6]) | ((unsigned)f2bf(h[8*k+7]) << 16);
        dst[k] = v;
    }
}

// ============================================================================
// 8) Layer 3: g3 = relu(BN2(h2)); h3 = W3(128x64) @ g3. No h3 materialization:
//    per (b,s) group (32 lanes) reduce max/min over n, and sum/sumsq for stats.
// ============================================================================
__global__ __launch_bounds__(256) void layer3_kernel(const unsigned short* __restrict__ h2,
    const float* __restrict__ ab2, const float* __restrict__ W3,
    float* __restrict__ hmax, float* __restrict__ hmin, float* __restrict__ sums3)
{
    __shared__ float ls[128], lq[128];
    const int tid = threadIdx.x;
    if (tid < 128) { ls[tid] = 0.f; lq[tid] = 0.f; }
    __syncthreads();
    const int col = blockIdx.x * 256 + tid;
    const int q = col >> 5;            // group (b*2048+s); lanes 0-31 / 32-63
    const uint4* src = (const uint4*)(h2 + (size_t)col * 64);
    float g[64];
#pragma unroll
    for (int k = 0; k < 8; ++k) {
        uint4 v = src[k];
        g[8*k+0] = bf2f(v.x & 0xffffu); g[8*k+1] = bf2f(v.x >> 16);
        g[8*k+2] = bf2f(v.y & 0xffffu); g[8*k+3] = bf2f(v.y >> 16);
        g[8*k+4] = bf2f(v.z & 0xffffu); g[8*k+5] = bf2f(v.z >> 16);
        g[8*k+6] = bf2f(v.w & 0xffffu); g[8*k+7] = bf2f(v.w >> 16);
    }
#pragma unroll
    for (int c = 0; c < 64; ++c)
        g[c] = fmaxf(fmaf(ab2[c*2], g[c], ab2[c*2+1]), 0.f);
#pragma unroll 2
    for (int o = 0; o < 128; ++o) {
        const float* w = W3 + (o << 6);
        float acc = 0.f;
#pragma unroll
        for (int c = 0; c < 64; ++c) acc = fmaf(w[c], g[c], acc);
        float sm = acc, sq = acc*acc, mx = acc, mn = acc;
#pragma unroll
        for (int off = 16; off >= 1; off >>= 1) {  // xor<32 stays in 32-lane half
            sm += __shfl_xor(sm, off);
            sq += __shfl_xor(sq, off);
            mx = fmaxf(mx, __shfl_xor(mx, off));
            mn = fminf(mn, __shfl_xor(mn, off));
        }
        if ((tid & 31) == 0) {
            hmax[(size_t)o * 16384 + q] = mx;
            hmin[(size_t)o * 16384 + q] = mn;
            atomicAdd(&ls[o], sm);
            atomicAdd(&lq[o], sq);
        }
    }
    __syncthreads();
    if (tid < 128) {
        atomicAdd(&sums3[tid*2+0], ls[tid]);
        atomicAdd(&sums3[tid*2+1], lq[tid]);
    }
}

// ============================================================================
// 9) Final: feats[b,o,s] = relu(a3*(a3>=0 ? max : min) + c3)
// ============================================================================
__global__ __launch_bounds__(256) void final_kernel(const float* __restrict__ hmax,
    const float* __restrict__ hmin, const float* __restrict__ ab3,
    float* __restrict__ out)
{
    const int t = blockIdx.x * 256 + threadIdx.x;   // (b,o,s), s fastest
    const int s = t & 2047;
    const int o = (t >> 11) & 127;
    const int b = t >> 18;
    const int q = (b << 11) + s;
    float a = ab3[o*2], c = ab3[o*2+1];
    float h = (a >= 0.f) ? hmax[(size_t)o * 16384 + q] : hmin[(size_t)o * 16384 + q];
    out[t] = fmaxf(fmaf(a, h, c), 0.f);
}

// ============================================================================
extern "C" void kernel_launch(void* const* d_in, const int* in_sizes, int n_in,
                              void* d_out, int out_size, void* d_ws, size_t ws_size,
                              hipStream_t stream) {
    (void)in_sizes; (void)n_in; (void)out_size; (void)ws_size;
    const float* xyz      = (const float*)d_in[0];
    const float* features = (const float*)d_in[1];
    const float* W1 = (const float*)d_in[2];
    const float* g1 = (const float*)d_in[3];
    const float* b1 = (const float*)d_in[4];
    const float* W2 = (const float*)d_in[5];
    const float* g2 = (const float*)d_in[6];
    const float* b2 = (const float*)d_in[7];
    const float* W3 = (const float*)d_in[8];
    const float* g3 = (const float*)d_in[9];
    const float* b3 = (const float*)d_in[10];

    char* ws = (char*)d_ws;
    float*          new_xyz = (float*)(ws + 0);                  // 196608 B
    int*            idx     = (int*)(ws + 196608);               // 2097152 B
    float*          ft      = (float*)(ws + 2293760);            // 16777216 B
    unsigned short* h1      = (unsigned short*)(ws + 19070976);  // 67108864 B
    unsigned short* h2      = (unsigned short*)(ws + 86179840);  // 67108864 B
    float*          hmax    = (float*)(ws + 153288704);          // 8388608 B
    float*          hmin    = (float*)(ws + 161677312);          // 8388608 B
    float*          sums    = (float*)(ws + 170065920);          // 2048 B (zeroed)
    float*          ab      = (float*)(ws + 170067968);          // 2048 B
    float* sums1 = sums;        float* ab1 = ab;
    float* sums2 = sums + 128;  float* ab2 = ab + 128;
    float* sums3 = sums + 256;  float* ab3 = ab + 256;

    float* out_newxyz = (float*)d_out;            // B*NS*3 = 49152 floats
    float* out_feats  = (float*)d_out + 49152;    // B*128*NS floats

    hipMemsetAsync(sums, 0, 2048, stream);

    fps_kernel<<<NB, 512, 0, stream>>>(xyz, new_xyz, out_newxyz);
    transpose_kernel<<<dim3(NN/64, NB), 256, 0, stream>>>(features, ft);
    ballquery_kernel<<<(NB*NS)/4, 256, 0, stream>>>(xyz, new_xyz, idx);
    layer1_kernel<<<NCOL/256, 256, 0, stream>>>(xyz, new_xyz, idx, ft, W1, h1);
    stats_kernel<<<1024, 256, 0, stream>>>(h1, sums1);
    finalize_kernel<<<1, 128, 0, stream>>>(sums1, g1, b1, ab1, 64);
    layer2_kernel<<<NCOL/256, 256, 0, stream>>>(h1, ab1, W2, h2);
    stats_kernel<<<1024, 256, 0, stream>>>(h2, sums2);
    finalize_kernel<<<1, 128, 0, stream>>>(sums2, g2, b2, ab2, 64);
    layer3_kernel<<<NCOL/256, 256, 0, stream>>>(h2, ab2, W3, hmax, hmin, sums3);
    finalize_kernel<<<1, 128, 0, stream>>>(sums3, g3, b3, ab3, 128);
    final_kernel<<<(NB*128*NS)/256, 256, 0, stream>>>(hmax, hmin, ab3, out_feats);
}

// Round 3
// 3205.437 us; speedup vs baseline: 1.5256x; 1.0402x over previous
//
#include <hip/hip_runtime.h>
#include <hip/hip_bf16.h>
#include <stdint.h>

#define NB 8
#define NN 8192
#define NC 64
#define NS 2048
#define NK 32
#define NCOL (NB*NS*NK)   // 524288 columns (b,s,n)

typedef float v2f __attribute__((ext_vector_type(2)));

// ---------- bf16 helpers (RNE) ----------
__device__ __forceinline__ unsigned short f2bf(float x) {
    union { float f; unsigned u; } c; c.f = x;
    unsigned r = c.u + 0x7fffu + ((c.u >> 16) & 1u);
    return (unsigned short)(r >> 16);
}
__device__ __forceinline__ float bf2f(unsigned v16) {
    union { float f; unsigned u; } c; c.u = v16 << 16;
    return c.f;
}

// ============================================================================
// 1) Furthest point sampling: one block per batch, 256 threads, 32 pts/thread.
//    Exact fp32 match: contract(off), (dx2+dy2)+dz2 order, argmax tie = first.
//    - float2 packed math -> v_pk_mul/add_f32 (halves distance-loop VALU)
//    - 4 chunked (val,j) accumulators break the dependent select chain;
//      contiguous j-ranges + strict '>' combine preserve first-max tie-break
//    - (value, ~index) u64 key: umax == argmax with smallest-index tie
//    - cross-wave: direct LDS reads of 4 wave keys + 3 local u64 maxes
//      (no second shuffle chain); ONE barrier/iter, parity double-buffer
// ============================================================================
__global__ __launch_bounds__(256, 1) void fps_kernel(const float* __restrict__ xyz,
    float* __restrict__ new_xyz, float* __restrict__ out_newxyz)
{
#pragma clang fp contract(off)
    const int b = blockIdx.x;
    const int tid = threadIdx.x;
    const float* xb = xyz + (size_t)b * NN * 3;
    __shared__ float sx[NN], sy[NN], sz[NN];            // 96 KB
    __shared__ unsigned long long s_key[2][4];
    v2f px[16], py[16], pz[16], dmin[16];
#pragma unroll
    for (int jj = 0; jj < 16; ++jj) {                    // pair (2jj, 2jj+1)
        int p0 = (2*jj)*256 + tid, p1 = p0 + 256;        // j-major: idx asc in j
        float x0 = xb[p0*3+0], y0 = xb[p0*3+1], z0 = xb[p0*3+2];
        float x1 = xb[p1*3+0], y1 = xb[p1*3+1], z1 = xb[p1*3+2];
        px[jj].x = x0; px[jj].y = x1;
        py[jj].x = y0; py[jj].y = y1;
        pz[jj].x = z0; pz[jj].y = z1;
        dmin[jj].x = 1e10f; dmin[jj].y = 1e10f;
        sx[p0] = x0; sy[p0] = y0; sz[p0] = z0;
        sx[p1] = x1; sy[p1] = y1; sz[p1] = z1;
    }
    float lx = xb[0], ly = xb[1], lz = xb[2];            // selection 0 = point 0
    if (tid == 0) {
        float* nw = new_xyz + (size_t)b * NS * 3;
        float* ow = out_newxyz + (size_t)b * NS * 3;
        nw[0] = lx; nw[1] = ly; nw[2] = lz;
        ow[0] = lx; ow[1] = ly; ow[2] = lz;
    }
    __syncthreads();                                     // sx/sy/sz visible
    for (int i = 1; i < NS; ++i) {
        v2f l2x; l2x.x = lx; l2x.y = lx;
        v2f l2y; l2y.x = ly; l2y.y = ly;
        v2f l2z; l2z.x = lz; l2z.y = lz;
        float bv0 = -1.f, bv1 = -1.f, bv2 = -1.f, bv3 = -1.f;
        int   bj0 = 0,    bj1 = 0,    bj2 = 0,    bj3 = 0;
#pragma unroll
        for (int jj = 0; jj < 16; ++jj) {
            v2f dx = px[jj] - l2x;                       // v_pk_add (neg)
            v2f dy = py[jj] - l2y;
            v2f dz = pz[jj] - l2z;
            v2f d = (dx*dx + dy*dy) + dz*dz;             // pk mul/add, exact order
            v2f dm;
            dm.x = fminf(dmin[jj].x, d.x);
            dm.y = fminf(dmin[jj].y, d.y);
            dmin[jj] = dm;
            // 4 accumulators over contiguous j-chunks; strict > = first max
            if ((jj >> 2) == 0) {
                if (dm.x > bv0) { bv0 = dm.x; bj0 = 2*jj; }
                if (dm.y > bv0) { bv0 = dm.y; bj0 = 2*jj+1; }
            } else if ((jj >> 2) == 1) {
                if (dm.x > bv1) { bv1 = dm.x; bj1 = 2*jj; }
                if (dm.y > bv1) { bv1 = dm.y; bj1 = 2*jj+1; }
            } else if ((jj >> 2) == 2) {
                if (dm.x > bv2) { bv2 = dm.x; bj2 = 2*jj; }
                if (dm.y > bv2) { bv2 = dm.y; bj2 = 2*jj+1; }
            } else {
                if (dm.x > bv3) { bv3 = dm.x; bj3 = 2*jj; }
                if (dm.y > bv3) { bv3 = dm.y; bj3 = 2*jj+1; }
            }
        }
        // combine chunks: strict > keeps lower chunk (smaller j) on tie
        if (bv1 > bv0) { bv0 = bv1; bj0 = bj1; }
        if (bv3 > bv2) { bv2 = bv3; bj2 = bj3; }
        if (bv2 > bv0) { bv0 = bv2; bj0 = bj2; }
        // pack: high32 = float bits (monotone, d>=0), low32 = ~pointidx
        unsigned long long key =
            ((unsigned long long)__float_as_uint(bv0) << 32)
            | (unsigned)(~((bj0 << 8) + tid));
#pragma unroll
        for (int off = 32; off >= 1; off >>= 1) {
            unsigned long long o = __shfl_xor(key, off);
            if (o > key) key = o;
        }
        if ((tid & 63) == 0) s_key[i & 1][tid >> 6] = key;
        __syncthreads();                                  // the ONLY barrier
        unsigned long long k0 = s_key[i & 1][0];
        unsigned long long k1 = s_key[i & 1][1];
        unsigned long long k2 = s_key[i & 1][2];
        unsigned long long k3 = s_key[i & 1][3];
        if (k1 > k0) k0 = k1;
        if (k3 > k2) k2 = k3;
        if (k2 > k0) k0 = k2;
        const int ix = (int)(~(unsigned)k0);
        lx = sx[ix]; ly = sy[ix]; lz = sz[ix];            // LDS broadcast read
        if (tid == 0) {
            float* nw = new_xyz + ((size_t)b * NS + i) * 3;
            float* ow = out_newxyz + ((size_t)b * NS + i) * 3;
            nw[0] = lx; nw[1] = ly; nw[2] = lz;
            ow[0] = lx; ow[1] = ly; ow[2] = lz;
        }
    }
}

// ============================================================================
// 2) Transpose features (B,C,N) -> (B,N,C) for contiguous per-point gathers.
// ============================================================================
__global__ __launch_bounds__(256) void transpose_kernel(const float* __restrict__ f,
    float* __restrict__ ft)
{
    __shared__ float tile[64][65];
    int b = blockIdx.y;
    int p0 = blockIdx.x * 64;
    for (int k = threadIdx.x; k < 64*64; k += 256) {
        int c = k >> 6, p = k & 63;
        tile[c][p] = f[((size_t)b * NC + c) * NN + p0 + p];
    }
    __syncthreads();
    for (int k = threadIdx.x; k < 64*64; k += 256) {
        int p = k >> 6, c = k & 63;
        ft[((size_t)b * NN + p0 + p) * NC + c] = tile[c][p];
    }
}

// ============================================================================
// 3) Ball query: one wave per (b,s) query. First 32 smallest in-ball indices,
//    pad with first. r2 must be float(0.2*0.2) = 0.0399999991 (not 0.2f*0.2f).
// ============================================================================
__global__ __launch_bounds__(256) void ballquery_kernel(const float* __restrict__ xyz,
    const float* __restrict__ new_xyz, int* __restrict__ idx)
{
#pragma clang fp contract(off)
    const int q = blockIdx.x * 4 + (threadIdx.x >> 6);
    const int lane = threadIdx.x & 63;
    const int b = q >> 11;
    const float r2 = (float)(0.2 * 0.2);
    const float* xb = xyz + (size_t)b * NN * 3;
    const float* nx = new_xyz + (size_t)q * 3;
    float qx = nx[0], qy = nx[1], qz = nx[2];
    int cnt = 0, first = -1;
    int* out = idx + (size_t)q * NK;
    for (int base = 0; base < NN; base += 64) {
        int p = base + lane;
        float x = xb[p*3+0], y = xb[p*3+1], z = xb[p*3+2];
        float dx = qx - x, dy = qy - y, dz = qz - z;
        float d2 = (dx*dx + dy*dy) + dz*dz;
        bool in = d2 < r2;
        unsigned long long m = __ballot(in);
        if (m) {
            if (first < 0) first = base + __builtin_ctzll(m);
            if (in) {
                int rank = cnt + __popcll(m & ((1ull << lane) - 1ull));
                if (rank < NK) out[rank] = p;
            }
            cnt += __popcll(m);
            if (cnt >= NK) break;
        }
    }
    for (int k = cnt + lane; k < NK; k += 64) out[k] = first;  // cnt>=1 always
}

// ============================================================================
// 4) Layer 1: h1 = W1(64x67) @ g, one thread per column (b,s,n). h1 bf16.
// ============================================================================
__global__ __launch_bounds__(256) void layer1_kernel(const float* __restrict__ xyz,
    const float* __restrict__ new_xyz, const int* __restrict__ idx,
    const float* __restrict__ ft, const float* __restrict__ W1,
    unsigned short* __restrict__ h1)
{
    const int col = blockIdx.x * 256 + threadIdx.x;
    const int b = col >> 16;
    const int s = (col >> 5) & 2047;
    const int p = idx[col];
    float g[67];
    {
        const float* nx = new_xyz + ((size_t)(b * NS + s)) * 3;
        const float* xp = xyz + ((size_t)(b * NN + p)) * 3;
        g[0] = xp[0] - nx[0]; g[1] = xp[1] - nx[1]; g[2] = xp[2] - nx[2];
    }
    const float4* fp = (const float4*)(ft + ((size_t)(b * NN + p)) * NC);
#pragma unroll
    for (int c4 = 0; c4 < 16; ++c4) {
        float4 v = fp[c4];
        g[3 + 4*c4 + 0] = v.x; g[3 + 4*c4 + 1] = v.y;
        g[3 + 4*c4 + 2] = v.z; g[3 + 4*c4 + 3] = v.w;
    }
    float h[64];
#pragma unroll 4
    for (int o = 0; o < 64; ++o) {
        const float* w = W1 + o * 67;
        float a = 0.f;
#pragma unroll
        for (int c = 0; c < 67; ++c) a = fmaf(w[c], g[c], a);
        h[o] = a;
    }
    uint4* dst = (uint4*)(h1 + (size_t)col * 64);
#pragma unroll
    for (int k = 0; k < 8; ++k) {
        uint4 v;
        v.x = (unsigned)f2bf(h[8*k+0]) | ((unsigned)f2bf(h[8*k+1]) << 16);
        v.y = (unsigned)f2bf(h[8*k+2]) | ((unsigned)f2bf(h[8*k+3]) << 16);
        v.z = (unsigned)f2bf(h[8*k+4]) | ((unsigned)f2bf(h[8*k+5]) << 16);
        v.w = (unsigned)f2bf(h[8*k+6]) | ((unsigned)f2bf(h[8*k+7]) << 16);
        dst[k] = v;
    }
}

// ============================================================================
// 5) Stats pass over a bf16 [col][64] tensor: per-channel sum / sumsq.
// ============================================================================
__global__ __launch_bounds__(256) void stats_kernel(const unsigned short* __restrict__ h,
    float* __restrict__ sums)
{
    __shared__ float ls[64], lq[64];
    const int tid = threadIdx.x;
    if (tid < 64) { ls[tid] = 0.f; lq[tid] = 0.f; }
    __syncthreads();
    float s[8] = {0,0,0,0,0,0,0,0}, q[8] = {0,0,0,0,0,0,0,0};
    const int gt = blockIdx.x * 256 + tid;
    const int G = gridDim.x * 256;            // multiple of 8 -> channel phase fixed
    const uint4* src = (const uint4*)h;
    const int nvec = NCOL * 8;                 // uint4s (8 bf16 each)
    for (int i = gt; i < nvec; i += G) {
        uint4 v = src[i];
        float f0 = bf2f(v.x & 0xffffu), f1 = bf2f(v.x >> 16);
        float f2 = bf2f(v.y & 0xffffu), f3 = bf2f(v.y >> 16);
        float f4 = bf2f(v.z & 0xffffu), f5 = bf2f(v.z >> 16);
        float f6 = bf2f(v.w & 0xffffu), f7 = bf2f(v.w >> 16);
        s[0] += f0; q[0] = fmaf(f0, f0, q[0]);
        s[1] += f1; q[1] = fmaf(f1, f1, q[1]);
        s[2] += f2; q[2] = fmaf(f2, f2, q[2]);
        s[3] += f3; q[3] = fmaf(f3, f3, q[3]);
        s[4] += f4; q[4] = fmaf(f4, f4, q[4]);
        s[5] += f5; q[5] = fmaf(f5, f5, q[5]);
        s[6] += f6; q[6] = fmaf(f6, f6, q[6]);
        s[7] += f7; q[7] = fmaf(f7, f7, q[7]);
    }
    const int obase = (tid & 7) * 8;
#pragma unroll
    for (int j = 0; j < 8; ++j) {
        atomicAdd(&ls[obase + j], s[j]);
        atomicAdd(&lq[obase + j], q[j]);
    }
    __syncthreads();
    if (tid < 64) {
        atomicAdd(&sums[tid*2+0], ls[tid]);
        atomicAdd(&sums[tid*2+1], lq[tid]);
    }
}

// ============================================================================
// 6) Finalize BN params: a = gamma/sqrt(var+eps), c = beta - mu*a.
// ============================================================================
__global__ void finalize_kernel(const float* __restrict__ sums,
    const float* __restrict__ gamma, const float* __restrict__ beta,
    float* __restrict__ ab, int nch)
{
    int c = threadIdx.x;
    if (c < nch) {
        const float invM = 1.0f / 524288.0f;
        float mu = sums[c*2] * invM;
        float var = sums[c*2+1] * invM - mu * mu;
        float a = gamma[c] / sqrtf(var + 1e-5f);
        ab[c*2+0] = a;
        ab[c*2+1] = fmaf(-mu, a, beta[c]);
    }
}

// ============================================================================
// 7) Layer 2: g2 = relu(BN1(h1)); h2 = W2(64x64) @ g2. h2 bf16.
// ============================================================================
__global__ __launch_bounds__(256) void layer2_kernel(const unsigned short* __restrict__ h1,
    const float* __restrict__ ab1, const float* __restrict__ W2,
    unsigned short* __restrict__ h2)
{
    const int col = blockIdx.x * 256 + threadIdx.x;
    const uint4* src = (const uint4*)(h1 + (size_t)col * 64);
    float g[64];
#pragma unroll
    for (int k = 0; k < 8; ++k) {
        uint4 v = src[k];
        g[8*k+0] = bf2f(v.x & 0xffffu); g[8*k+1] = bf2f(v.x >> 16);
        g[8*k+2] = bf2f(v.y & 0xffffu); g[8*k+3] = bf2f(v.y >> 16);
        g[8*k+4] = bf2f(v.z & 0xffffu); g[8*k+5] = bf2f(v.z >> 16);
        g[8*k+6] = bf2f(v.w & 0xffffu); g[8*k+7] = bf2f(v.w >> 16);
    }
#pragma unroll
    for (int c = 0; c < 64; ++c)
        g[c] = fmaxf(fmaf(ab1[c*2], g[c], ab1[c*2+1]), 0.f);
    float h[64];
#pragma unroll 4
    for (int o = 0; o < 64; ++o) {
        const float* w = W2 + (o << 6);
        float a = 0.f;
#pragma unroll
        for (int c = 0; c < 64; ++c) a = fmaf(w[c], g[c], a);
        h[o] = a;
    }
    uint4* dst = (uint4*)(h2 + (size_t)col * 64);
#pragma unroll
    for (int k = 0; k < 8; ++k) {
        uint4 v;
        v.x = (unsigned)f2bf(h[8*k+0]) | ((unsigned)f2bf(h[8*k+1]) << 16);
        v.y = (unsigned)f2bf(h[8*k+2]) | ((unsigned)f2bf(h[8*k+3]) << 16);
        v.z = (unsigned)f2bf(h[8*k+4]) | ((unsigned)f2bf(h[8*k+5]) << 16);
        v.w = (unsigned)f2bf(h[8*k+6]) | ((unsigned)f2bf(h[8*k+7]) << 16);
        dst[k] = v;
    }
}

// ============================================================================
// 8) Layer 3: g3 = relu(BN2(h2)); h3 = W3(128x64) @ g3. No h3 materialization:
//    per (b,s) group (32 lanes) reduce max/min over n, and sum/sumsq for stats.
// ============================================================================
__global__ __launch_bounds__(256) void layer3_kernel(const unsigned short* __restrict__ h2,
    const float* __restrict__ ab2, const float* __restrict__ W3,
    float* __restrict__ hmax, float* __restrict__ hmin, float* __restrict__ sums3)
{
    __shared__ float ls[128], lq[128];
    const int tid = threadIdx.x;
    if (tid < 128) { ls[tid] = 0.f; lq[tid] = 0.f; }
    __syncthreads();
    const int col = blockIdx.x * 256 + tid;
    const int q = col >> 5;            // group (b*2048+s); lanes 0-31 / 32-63
    const uint4* src = (const uint4*)(h2 + (size_t)col * 64);
    float g[64];
#pragma unroll
    for (int k = 0; k < 8; ++k) {
        uint4 v = src[k];
        g[8*k+0] = bf2f(v.x & 0xffffu); g[8*k+1] = bf2f(v.x >> 16);
        g[8*k+2] = bf2f(v.y & 0xffffu); g[8*k+3] = bf2f(v.y >> 16);
        g[8*k+4] = bf2f(v.z & 0xffffu); g[8*k+5] = bf2f(v.z >> 16);
        g[8*k+6] = bf2f(v.w & 0xffffu); g[8*k+7] = bf2f(v.w >> 16);
    }
#pragma unroll
    for (int c = 0; c < 64; ++c)
        g[c] = fmaxf(fmaf(ab2[c*2], g[c], ab2[c*2+1]), 0.f);
#pragma unroll 2
    for (int o = 0; o < 128; ++o) {
        const float* w = W3 + (o << 6);
        float acc = 0.f;
#pragma unroll
        for (int c = 0; c < 64; ++c) acc = fmaf(w[c], g[c], acc);
        float sm = acc, sq = acc*acc, mx = acc, mn = acc;
#pragma unroll
        for (int off = 16; off >= 1; off >>= 1) {  // xor<32 stays in 32-lane half
            sm += __shfl_xor(sm, off);
            sq += __shfl_xor(sq, off);
            mx = fmaxf(mx, __shfl_xor(mx, off));
            mn = fminf(mn, __shfl_xor(mn, off));
        }
        if ((tid & 31) == 0) {
            hmax[(size_t)o * 16384 + q] = mx;
            hmin[(size_t)o * 16384 + q] = mn;
            atomicAdd(&ls[o], sm);
            atomicAdd(&lq[o], sq);
        }
    }
    __syncthreads();
    if (tid < 128) {
        atomicAdd(&sums3[tid*2+0], ls[tid]);
        atomicAdd(&sums3[tid*2+1], lq[tid]);
    }
}

// ============================================================================
// 9) Final: feats[b,o,s] = relu(a3*(a3>=0 ? max : min) + c3)
// ============================================================================
__global__ __launch_bounds__(256) void final_kernel(const float* __restrict__ hmax,
    const float* __restrict__ hmin, const float* __restrict__ ab3,
    float* __restrict__ out)
{
    const int t = blockIdx.x * 256 + threadIdx.x;   // (b,o,s), s fastest
    const int s = t & 2047;
    const int o = (t >> 11) & 127;
    const int b = t >> 18;
    const int q = (b << 11) + s;
    float a = ab3[o*2], c = ab3[o*2+1];
    float h = (a >= 0.f) ? hmax[(size_t)o * 16384 + q] : hmin[(size_t)o * 16384 + q];
    out[t] = fmaxf(fmaf(a, h, c), 0.f);
}

// ============================================================================
extern "C" void kernel_launch(void* const* d_in, const int* in_sizes, int n_in,
                              void* d_out, int out_size, void* d_ws, size_t ws_size,
                              hipStream_t stream) {
    (void)in_sizes; (void)n_in; (void)out_size; (void)ws_size;
    const float* xyz      = (const float*)d_in[0];
    const float* features = (const float*)d_in[1];
    const float* W1 = (const float*)d_in[2];
    const float* g1 = (const float*)d_in[3];
    const float* b1 = (const float*)d_in[4];
    const float* W2 = (const float*)d_in[5];
    const float* g2 = (const float*)d_in[6];
    const float* b2 = (const float*)d_in[7];
    const float* W3 = (const float*)d_in[8];
    const float* g3 = (const float*)d_in[9];
    const float* b3 = (const float*)d_in[10];

    char* ws = (char*)d_ws;
    float*          new_xyz = (float*)(ws + 0);                  // 196608 B
    int*            idx     = (int*)(ws + 196608);               // 2097152 B
    float*          ft      = (float*)(ws + 2293760);            // 16777216 B
    unsigned short* h1      = (unsigned short*)(ws + 19070976);  // 67108864 B
    unsigned short* h2      = (unsigned short*)(ws + 86179840);  // 67108864 B
    float*          hmax    = (float*)(ws + 153288704);          // 8388608 B
    float*          hmin    = (float*)(ws + 161677312);          // 8388608 B
    float*          sums    = (float*)(ws + 170065920);          // 2048 B (zeroed)
    float*          ab      = (float*)(ws + 170067968);          // 2048 B
    float* sums1 = sums;        float* ab1 = ab;
    float* sums2 = sums + 128;  float* ab2 = ab + 128;
    float* sums3 = sums + 256;  float* ab3 = ab + 256;

    float* out_newxyz = (float*)d_out;            // B*NS*3 = 49152 floats
    float* out_feats  = (float*)d_out + 49152;    // B*128*NS floats

    hipMemsetAsync(sums, 0, 2048, stream);

    fps_kernel<<<NB, 256, 0, stream>>>(xyz, new_xyz, out_newxyz);
    transpose_kernel<<<dim3(NN/64, NB), 256, 0, stream>>>(features, ft);
    ballquery_kernel<<<(NB*NS)/4, 256, 0, stream>>>(xyz, new_xyz, idx);
    layer1_kernel<<<NCOL/256, 256, 0, stream>>>(xyz, new_xyz, idx, ft, W1, h1);
    stats_kernel<<<1024, 256, 0, stream>>>(h1, sums1);
    finalize_kernel<<<1, 128, 0, stream>>>(sums1, g1, b1, ab1, 64);
    layer2_kernel<<<NCOL/256, 256, 0, stream>>>(h1, ab1, W2, h2);
    stats_kernel<<<1024, 256, 0, stream>>>(h2, sums2);
    finalize_kernel<<<1, 128, 0, stream>>>(sums2, g2, b2, ab2, 64);
    layer3_kernel<<<NCOL/256, 256, 0, stream>>>(h2, ab2, W3, hmax, hmin, sums3);
    finalize_kernel<<<1, 128, 0, stream>>>(sums3, g3, b3, ab3, 128);
    final_kernel<<<(NB*128*NS)/256, 256, 0, stream>>>(hmax, hmin, ab3, out_feats);
}

// Round 4
// 2547.509 us; speedup vs baseline: 1.9196x; 1.2583x over previous
//
#include <hip/hip_runtime.h>
#include <hip/hip_bf16.h>
#include <stdint.h>

#define NB 8
#define NN 8192
#define NC 64
#define NS 2048
#define NK 32
#define NCOL (NB*NS*NK)   // 524288 columns (b,s,n)

typedef float v2f __attribute__((ext_vector_type(2)));

// ---------- bf16 helpers (RNE) ----------
__device__ __forceinline__ unsigned short f2bf(float x) {
    union { float f; unsigned u; } c; c.f = x;
    unsigned r = c.u + 0x7fffu + ((c.u >> 16) & 1u);
    return (unsigned short)(r >> 16);
}
__device__ __forceinline__ float bf2f(unsigned v16) {
    union { float f; unsigned u; } c; c.u = v16 << 16;
    return c.f;
}

// ---------- DPP cross-lane helpers (VALU-speed, no LDS) ----------
// row_shr:n = 0x110|n, row_bcast15 = 0x142, row_bcast31 = 0x143
template<int CTRL>
__device__ __forceinline__ unsigned long long dpp_max_u64(unsigned long long key) {
    int olo = __builtin_amdgcn_update_dpp(0, (int)(unsigned)key,        CTRL, 0xf, 0xf, true);
    int ohi = __builtin_amdgcn_update_dpp(0, (int)(unsigned)(key >> 32), CTRL, 0xf, 0xf, true);
    unsigned long long ok = ((unsigned long long)(unsigned)ohi << 32) | (unsigned)olo;
    return ok > key ? ok : key;   // zero-fill loses to every real key
}
template<int CTRL>
__device__ __forceinline__ float dpp_add_f32(float x) {   // zero-fill identity
    int o = __builtin_amdgcn_update_dpp(0, __float_as_int(x), CTRL, 0xf, 0xf, true);
    return x + __int_as_float(o);
}
template<int CTRL>
__device__ __forceinline__ float dpp_max_f32(float x) {   // self identity
    int o = __builtin_amdgcn_update_dpp(__float_as_int(x), __float_as_int(x), CTRL, 0xf, 0xf, false);
    return fmaxf(x, __int_as_float(o));
}
template<int CTRL>
__device__ __forceinline__ float dpp_min_f32(float x) {   // self identity
    int o = __builtin_amdgcn_update_dpp(__float_as_int(x), __float_as_int(x), CTRL, 0xf, 0xf, false);
    return fminf(x, __int_as_float(o));
}
__device__ __forceinline__ v2f relu2(v2f v) {
    v.x = fmaxf(v.x, 0.f); v.y = fmaxf(v.y, 0.f); return v;
}

// ============================================================================
// 1) Furthest point sampling: one block per batch, 256 threads, 32 pts/thread.
//    Exact fp32 match: contract(off), (dx2+dy2)+dz2 order, argmax tie = first.
//    In-wave argmax via DPP (row_shr cascade + row_bcast) on (val,~idx) u64
//    keys -> lane 63 holds wave max at VALU latency (no ds_permute chain).
//    ONE barrier/iter; parity double-buffered wave keys; coords from LDS.
// ============================================================================
__global__ __launch_bounds__(256, 1) void fps_kernel(const float* __restrict__ xyz,
    float* __restrict__ new_xyz, float* __restrict__ out_newxyz)
{
#pragma clang fp contract(off)
    const int b = blockIdx.x;
    const int tid = threadIdx.x;
    const float* xb = xyz + (size_t)b * NN * 3;
    __shared__ float sx[NN], sy[NN], sz[NN];            // 96 KB
    __shared__ unsigned long long s_key[2][4];
    v2f px[16], py[16], pz[16], dmin[16];
#pragma unroll
    for (int jj = 0; jj < 16; ++jj) {                    // pair (2jj, 2jj+1)
        int p0 = (2*jj)*256 + tid, p1 = p0 + 256;        // j-major: idx asc in j
        float x0 = xb[p0*3+0], y0 = xb[p0*3+1], z0 = xb[p0*3+2];
        float x1 = xb[p1*3+0], y1 = xb[p1*3+1], z1 = xb[p1*3+2];
        px[jj].x = x0; px[jj].y = x1;
        py[jj].x = y0; py[jj].y = y1;
        pz[jj].x = z0; pz[jj].y = z1;
        dmin[jj].x = 1e10f; dmin[jj].y = 1e10f;
        sx[p0] = x0; sy[p0] = y0; sz[p0] = z0;
        sx[p1] = x1; sy[p1] = y1; sz[p1] = z1;
    }
    float lx = xb[0], ly = xb[1], lz = xb[2];            // selection 0 = point 0
    if (tid == 0) {
        float* nw = new_xyz + (size_t)b * NS * 3;
        float* ow = out_newxyz + (size_t)b * NS * 3;
        nw[0] = lx; nw[1] = ly; nw[2] = lz;
        ow[0] = lx; ow[1] = ly; ow[2] = lz;
    }
    __syncthreads();                                     // sx/sy/sz visible
    for (int i = 1; i < NS; ++i) {
        v2f l2x; l2x.x = lx; l2x.y = lx;
        v2f l2y; l2y.x = ly; l2y.y = ly;
        v2f l2z; l2z.x = lz; l2z.y = lz;
        float bv0 = -1.f, bv1 = -1.f, bv2 = -1.f, bv3 = -1.f;
        int   bj0 = 0,    bj1 = 0,    bj2 = 0,    bj3 = 0;
#pragma unroll
        for (int jj = 0; jj < 16; ++jj) {
            v2f dx = px[jj] - l2x;
            v2f dy = py[jj] - l2y;
            v2f dz = pz[jj] - l2z;
            v2f d = (dx*dx + dy*dy) + dz*dz;             // pk mul/add, exact order
            v2f dm;
            dm.x = fminf(dmin[jj].x, d.x);
            dm.y = fminf(dmin[jj].y, d.y);
            dmin[jj] = dm;
            // 4 accumulators over contiguous j-chunks; strict > = first max
            if ((jj >> 2) == 0) {
                if (dm.x > bv0) { bv0 = dm.x; bj0 = 2*jj; }
                if (dm.y > bv0) { bv0 = dm.y; bj0 = 2*jj+1; }
            } else if ((jj >> 2) == 1) {
                if (dm.x > bv1) { bv1 = dm.x; bj1 = 2*jj; }
                if (dm.y > bv1) { bv1 = dm.y; bj1 = 2*jj+1; }
            } else if ((jj >> 2) == 2) {
                if (dm.x > bv2) { bv2 = dm.x; bj2 = 2*jj; }
                if (dm.y > bv2) { bv2 = dm.y; bj2 = 2*jj+1; }
            } else {
                if (dm.x > bv3) { bv3 = dm.x; bj3 = 2*jj; }
                if (dm.y > bv3) { bv3 = dm.y; bj3 = 2*jj+1; }
            }
        }
        if (bv1 > bv0) { bv0 = bv1; bj0 = bj1; }
        if (bv3 > bv2) { bv2 = bv3; bj2 = bj3; }
        if (bv2 > bv0) { bv0 = bv2; bj0 = bj2; }
        // pack: high32 = float bits (monotone, d>=0), low32 = ~pointidx
        unsigned long long key =
            ((unsigned long long)__float_as_uint(bv0) << 32)
            | (unsigned)(~((bj0 << 8) + tid));
        // DPP wave64 max-reduce -> lane 63
        key = dpp_max_u64<0x111>(key);   // row_shr:1
        key = dpp_max_u64<0x112>(key);   // row_shr:2
        key = dpp_max_u64<0x114>(key);   // row_shr:4
        key = dpp_max_u64<0x118>(key);   // row_shr:8
        key = dpp_max_u64<0x142>(key);   // row_bcast:15
        key = dpp_max_u64<0x143>(key);   // row_bcast:31
        if ((tid & 63) == 63) s_key[i & 1][tid >> 6] = key;
        __syncthreads();                                  // the ONLY barrier
        unsigned long long k0 = s_key[i & 1][0];
        unsigned long long k1 = s_key[i & 1][1];
        unsigned long long k2 = s_key[i & 1][2];
        unsigned long long k3 = s_key[i & 1][3];
        if (k1 > k0) k0 = k1;
        if (k3 > k2) k2 = k3;
        if (k2 > k0) k0 = k2;
        const int ix = (int)(~(unsigned)k0);
        lx = sx[ix]; ly = sy[ix]; lz = sz[ix];            // LDS broadcast read
        if (tid == 0) {
            float* nw = new_xyz + ((size_t)b * NS + i) * 3;
            float* ow = out_newxyz + ((size_t)b * NS + i) * 3;
            nw[0] = lx; nw[1] = ly; nw[2] = lz;
            ow[0] = lx; ow[1] = ly; ow[2] = lz;
        }
    }
}

// ============================================================================
// 2) Transpose features (B,C,N) -> (B,N,C) for contiguous per-point gathers.
// ============================================================================
__global__ __launch_bounds__(256) void transpose_kernel(const float* __restrict__ f,
    float* __restrict__ ft)
{
    __shared__ float tile[64][65];
    int b = blockIdx.y;
    int p0 = blockIdx.x * 64;
    for (int k = threadIdx.x; k < 64*64; k += 256) {
        int c = k >> 6, p = k & 63;
        tile[c][p] = f[((size_t)b * NC + c) * NN + p0 + p];
    }
    __syncthreads();
    for (int k = threadIdx.x; k < 64*64; k += 256) {
        int p = k >> 6, c = k & 63;
        ft[((size_t)b * NN + p0 + p) * NC + c] = tile[c][p];
    }
}

// ============================================================================
// 3) Ball query: one wave per (b,s) query. First 32 smallest in-ball indices,
//    pad with first. r2 must be float(0.2*0.2) = 0.0399999991 (not 0.2f*0.2f).
// ============================================================================
__global__ __launch_bounds__(256) void ballquery_kernel(const float* __restrict__ xyz,
    const float* __restrict__ new_xyz, int* __restrict__ idx)
{
#pragma clang fp contract(off)
    const int q = blockIdx.x * 4 + (threadIdx.x >> 6);
    const int lane = threadIdx.x & 63;
    const int b = q >> 11;
    const float r2 = (float)(0.2 * 0.2);
    const float* xb = xyz + (size_t)b * NN * 3;
    const float* nx = new_xyz + (size_t)q * 3;
    float qx = nx[0], qy = nx[1], qz = nx[2];
    int cnt = 0, first = -1;
    int* out = idx + (size_t)q * NK;
    for (int base = 0; base < NN; base += 64) {
        int p = base + lane;
        float x = xb[p*3+0], y = xb[p*3+1], z = xb[p*3+2];
        float dx = qx - x, dy = qy - y, dz = qz - z;
        float d2 = (dx*dx + dy*dy) + dz*dz;
        bool in = d2 < r2;
        unsigned long long m = __ballot(in);
        if (m) {
            if (first < 0) first = base + __builtin_ctzll(m);
            if (in) {
                int rank = cnt + __popcll(m & ((1ull << lane) - 1ull));
                if (rank < NK) out[rank] = p;
            }
            cnt += __popcll(m);
            if (cnt >= NK) break;
        }
    }
    for (int k = cnt + lane; k < NK; k += 64) out[k] = first;  // cnt>=1 always
}

// ============================================================================
// 4) Layer 1: h1 = W1(64x67) @ g. v2f packed FMAs; h computed in two halves
//    of 32 outputs to keep VGPR below spill point. h1 bf16.
// ============================================================================
__global__ __launch_bounds__(256, 2) void layer1_kernel(const float* __restrict__ xyz,
    const float* __restrict__ new_xyz, const int* __restrict__ idx,
    const float* __restrict__ ft, const float* __restrict__ W1,
    unsigned short* __restrict__ h1)
{
    const int col = blockIdx.x * 256 + threadIdx.x;
    const int b = col >> 16;
    const int s = (col >> 5) & 2047;
    const int p = idx[col];
    v2f g[34];
    float* gf = (float*)g;
    {
        const float* nx = new_xyz + ((size_t)(b * NS + s)) * 3;
        const float* xp = xyz + ((size_t)(b * NN + p)) * 3;
        gf[0] = xp[0] - nx[0]; gf[1] = xp[1] - nx[1]; gf[2] = xp[2] - nx[2];
    }
    const float4* fp = (const float4*)(ft + ((size_t)(b * NN + p)) * NC);
#pragma unroll
    for (int c4 = 0; c4 < 16; ++c4) {
        float4 v = fp[c4];
        gf[3 + 4*c4 + 0] = v.x; gf[3 + 4*c4 + 1] = v.y;
        gf[3 + 4*c4 + 2] = v.z; gf[3 + 4*c4 + 3] = v.w;
    }
    gf[67] = 0.f;
    uint4* dst = (uint4*)(h1 + (size_t)col * 64);
#pragma unroll
    for (int half = 0; half < 2; ++half) {
        float h[32];
#pragma unroll 4
        for (int o16 = 0; o16 < 32; ++o16) {
            const float* w = W1 + (half*32 + o16) * 67;
            v2f acc; acc.x = 0.f; acc.y = 0.f;
#pragma unroll
            for (int k = 0; k < 33; ++k) {
                v2f wv; wv.x = w[2*k]; wv.y = w[2*k+1];
                acc = wv * g[k] + acc;                    // v_pk_fma_f32
            }
            h[o16] = fmaf(w[66], gf[66], acc.x + acc.y);
        }
#pragma unroll
        for (int k = 0; k < 4; ++k) {
            uint4 v;
            v.x = (unsigned)f2bf(h[8*k+0]) | ((unsigned)f2bf(h[8*k+1]) << 16);
            v.y = (unsigned)f2bf(h[8*k+2]) | ((unsigned)f2bf(h[8*k+3]) << 16);
            v.z = (unsigned)f2bf(h[8*k+4]) | ((unsigned)f2bf(h[8*k+5]) << 16);
            v.w = (unsigned)f2bf(h[8*k+6]) | ((unsigned)f2bf(h[8*k+7]) << 16);
            dst[half*4 + k] = v;
        }
    }
}

// ============================================================================
// 5) Stats pass over a bf16 [col][64] tensor: per-channel sum / sumsq.
// ============================================================================
__global__ __launch_bounds__(256) void stats_kernel(const unsigned short* __restrict__ h,
    float* __restrict__ sums)
{
    __shared__ float ls[64], lq[64];
    const int tid = threadIdx.x;
    if (tid < 64) { ls[tid] = 0.f; lq[tid] = 0.f; }
    __syncthreads();
    float s[8] = {0,0,0,0,0,0,0,0}, q[8] = {0,0,0,0,0,0,0,0};
    const int gt = blockIdx.x * 256 + tid;
    const int G = gridDim.x * 256;            // multiple of 8 -> channel phase fixed
    const uint4* src = (const uint4*)h;
    const int nvec = NCOL * 8;                 // uint4s (8 bf16 each)
    for (int i = gt; i < nvec; i += G) {
        uint4 v = src[i];
        float f0 = bf2f(v.x & 0xffffu), f1 = bf2f(v.x >> 16);
        float f2 = bf2f(v.y & 0xffffu), f3 = bf2f(v.y >> 16);
        float f4 = bf2f(v.z & 0xffffu), f5 = bf2f(v.z >> 16);
        float f6 = bf2f(v.w & 0xffffu), f7 = bf2f(v.w >> 16);
        s[0] += f0; q[0] = fmaf(f0, f0, q[0]);
        s[1] += f1; q[1] = fmaf(f1, f1, q[1]);
        s[2] += f2; q[2] = fmaf(f2, f2, q[2]);
        s[3] += f3; q[3] = fmaf(f3, f3, q[3]);
        s[4] += f4; q[4] = fmaf(f4, f4, q[4]);
        s[5] += f5; q[5] = fmaf(f5, f5, q[5]);
        s[6] += f6; q[6] = fmaf(f6, f6, q[6]);
        s[7] += f7; q[7] = fmaf(f7, f7, q[7]);
    }
    const int obase = (tid & 7) * 8;
#pragma unroll
    for (int j = 0; j < 8; ++j) {
        atomicAdd(&ls[obase + j], s[j]);
        atomicAdd(&lq[obase + j], q[j]);
    }
    __syncthreads();
    if (tid < 64) {
        atomicAdd(&sums[tid*2+0], ls[tid]);
        atomicAdd(&sums[tid*2+1], lq[tid]);
    }
}

// ============================================================================
// 6) Finalize BN params. Layout: ab[c] = a_c (scale), ab[nch+c] = b_c (shift)
//    so the apply step can use packed v2f math.
// ============================================================================
__global__ void finalize_kernel(const float* __restrict__ sums,
    const float* __restrict__ gamma, const float* __restrict__ beta,
    float* __restrict__ ab, int nch)
{
    int c = threadIdx.x;
    if (c < nch) {
        const float invM = 1.0f / 524288.0f;
        float mu = sums[c*2] * invM;
        float var = sums[c*2+1] * invM - mu * mu;
        float a = gamma[c] / sqrtf(var + 1e-5f);
        ab[c] = a;
        ab[nch + c] = fmaf(-mu, a, beta[c]);
    }
}

// ============================================================================
// 7) Layer 2: g2 = relu(BN1(h1)); h2 = W2(64x64) @ g2. Packed FMAs, halves.
// ============================================================================
__global__ __launch_bounds__(256, 2) void layer2_kernel(const unsigned short* __restrict__ h1,
    const float* __restrict__ ab1, const float* __restrict__ W2,
    unsigned short* __restrict__ h2)
{
    const int col = blockIdx.x * 256 + threadIdx.x;
    const uint4* src = (const uint4*)(h1 + (size_t)col * 64);
    v2f g[32];
    float* gf = (float*)g;
#pragma unroll
    for (int k = 0; k < 8; ++k) {
        uint4 v = src[k];
        gf[8*k+0] = bf2f(v.x & 0xffffu); gf[8*k+1] = bf2f(v.x >> 16);
        gf[8*k+2] = bf2f(v.y & 0xffffu); gf[8*k+3] = bf2f(v.y >> 16);
        gf[8*k+4] = bf2f(v.z & 0xffffu); gf[8*k+5] = bf2f(v.z >> 16);
        gf[8*k+6] = bf2f(v.w & 0xffffu); gf[8*k+7] = bf2f(v.w >> 16);
    }
    const v2f* a2 = (const v2f*)ab1;
    const v2f* b2 = (const v2f*)(ab1 + 64);
#pragma unroll
    for (int k = 0; k < 32; ++k)
        g[k] = relu2(a2[k] * g[k] + b2[k]);               // pk_fma + pk_max
    uint4* dst = (uint4*)(h2 + (size_t)col * 64);
#pragma unroll
    for (int half = 0; half < 2; ++half) {
        float h[32];
#pragma unroll 4
        for (int o16 = 0; o16 < 32; ++o16) {
            const float* w = W2 + ((half*32 + o16) << 6);
            v2f acc; acc.x = 0.f; acc.y = 0.f;
#pragma unroll
            for (int k = 0; k < 32; ++k) {
                v2f wv; wv.x = w[2*k]; wv.y = w[2*k+1];
                acc = wv * g[k] + acc;
            }
            h[o16] = acc.x + acc.y;
        }
#pragma unroll
        for (int k = 0; k < 4; ++k) {
            uint4 v;
            v.x = (unsigned)f2bf(h[8*k+0]) | ((unsigned)f2bf(h[8*k+1]) << 16);
            v.y = (unsigned)f2bf(h[8*k+2]) | ((unsigned)f2bf(h[8*k+3]) << 16);
            v.z = (unsigned)f2bf(h[8*k+4]) | ((unsigned)f2bf(h[8*k+5]) << 16);
            v.w = (unsigned)f2bf(h[8*k+6]) | ((unsigned)f2bf(h[8*k+7]) << 16);
            dst[half*4 + k] = v;
        }
    }
}

// ============================================================================
// 8) Layer 3: g3 = relu(BN2(h2)); h3 = W3(128x64) @ g3; per-(b,s) max/min over
//    n=32 (lanes) + channel stats — all reductions via DPP (no ds ops).
//    After shr1..8 + bcast15: lane31 holds lanes0-31 reduce, lane63 holds 32-63.
// ============================================================================
__global__ __launch_bounds__(256, 2) void layer3_kernel(const unsigned short* __restrict__ h2,
    const float* __restrict__ ab2, const float* __restrict__ W3,
    float* __restrict__ hmax, float* __restrict__ hmin, float* __restrict__ sums3)
{
    __shared__ float ls[128], lq[128];
    const int tid = threadIdx.x;
    if (tid < 128) { ls[tid] = 0.f; lq[tid] = 0.f; }
    __syncthreads();
    const int col = blockIdx.x * 256 + tid;
    const int q = col >> 5;            // group (b*2048+s); lanes 0-31 / 32-63
    const uint4* src = (const uint4*)(h2 + (size_t)col * 64);
    v2f g[32];
    float* gf = (float*)g;
#pragma unroll
    for (int k = 0; k < 8; ++k) {
        uint4 v = src[k];
        gf[8*k+0] = bf2f(v.x & 0xffffu); gf[8*k+1] = bf2f(v.x >> 16);
        gf[8*k+2] = bf2f(v.y & 0xffffu); gf[8*k+3] = bf2f(v.y >> 16);
        gf[8*k+4] = bf2f(v.z & 0xffffu); gf[8*k+5] = bf2f(v.z >> 16);
        gf[8*k+6] = bf2f(v.w & 0xffffu); gf[8*k+7] = bf2f(v.w >> 16);
    }
    const v2f* a2 = (const v2f*)ab2;
    const v2f* b2 = (const v2f*)(ab2 + 64);
#pragma unroll
    for (int k = 0; k < 32; ++k)
        g[k] = relu2(a2[k] * g[k] + b2[k]);
    const bool leader = ((tid & 31) == 31);
#pragma unroll 2
    for (int o = 0; o < 128; ++o) {
        const float* w = W3 + (o << 6);
        v2f acc; acc.x = 0.f; acc.y = 0.f;
#pragma unroll
        for (int k = 0; k < 32; ++k) {
            v2f wv; wv.x = w[2*k]; wv.y = w[2*k+1];
            acc = wv * g[k] + acc;
        }
        float hv = acc.x + acc.y;
        float sm = hv, sq = hv*hv, mx = hv, mn = hv;
        sm = dpp_add_f32<0x111>(sm); sq = dpp_add_f32<0x111>(sq);
        mx = dpp_max_f32<0x111>(mx); mn = dpp_min_f32<0x111>(mn);
        sm = dpp_add_f32<0x112>(sm); sq = dpp_add_f32<0x112>(sq);
        mx = dpp_max_f32<0x112>(mx); mn = dpp_min_f32<0x112>(mn);
        sm = dpp_add_f32<0x114>(sm); sq = dpp_add_f32<0x114>(sq);
        mx = dpp_max_f32<0x114>(mx); mn = dpp_min_f32<0x114>(mn);
        sm = dpp_add_f32<0x118>(sm); sq = dpp_add_f32<0x118>(sq);
        mx = dpp_max_f32<0x118>(mx); mn = dpp_min_f32<0x118>(mn);
        sm = dpp_add_f32<0x142>(sm); sq = dpp_add_f32<0x142>(sq);
        mx = dpp_max_f32<0x142>(mx); mn = dpp_min_f32<0x142>(mn);
        if (leader) {
            hmax[(size_t)o * 16384 + q] = mx;
            hmin[(size_t)o * 16384 + q] = mn;
            atomicAdd(&ls[o], sm);
            atomicAdd(&lq[o], sq);
        }
    }
    __syncthreads();
    if (tid < 128) {
        atomicAdd(&sums3[tid*2+0], ls[tid]);
        atomicAdd(&sums3[tid*2+1], lq[tid]);
    }
}

// ============================================================================
// 9) Final: feats[b,o,s] = relu(a3*(a3>=0 ? max : min) + c3)
// ============================================================================
__global__ __launch_bounds__(256) void final_kernel(const float* __restrict__ hmax,
    const float* __restrict__ hmin, const float* __restrict__ ab3,
    float* __restrict__ out)
{
    const int t = blockIdx.x * 256 + threadIdx.x;   // (b,o,s), s fastest
    const int s = t & 2047;
    const int o = (t >> 11) & 127;
    const int b = t >> 18;
    const int q = (b << 11) + s;
    float a = ab3[o], c = ab3[128 + o];
    float h = (a >= 0.f) ? hmax[(size_t)o * 16384 + q] : hmin[(size_t)o * 16384 + q];
    out[t] = fmaxf(fmaf(a, h, c), 0.f);
}

// ============================================================================
extern "C" void kernel_launch(void* const* d_in, const int* in_sizes, int n_in,
                              void* d_out, int out_size, void* d_ws, size_t ws_size,
                              hipStream_t stream) {
    (void)in_sizes; (void)n_in; (void)out_size; (void)ws_size;
    const float* xyz      = (const float*)d_in[0];
    const float* features = (const float*)d_in[1];
    const float* W1 = (const float*)d_in[2];
    const float* g1 = (const float*)d_in[3];
    const float* b1 = (const float*)d_in[4];
    const float* W2 = (const float*)d_in[5];
    const float* g2 = (const float*)d_in[6];
    const float* b2 = (const float*)d_in[7];
    const float* W3 = (const float*)d_in[8];
    const float* g3 = (const float*)d_in[9];
    const float* b3 = (const float*)d_in[10];

    char* ws = (char*)d_ws;
    float*          new_xyz = (float*)(ws + 0);                  // 196608 B
    int*            idx     = (int*)(ws + 196608);               // 2097152 B
    float*          ft      = (float*)(ws + 2293760);            // 16777216 B
    unsigned short* h1      = (unsigned short*)(ws + 19070976);  // 67108864 B
    unsigned short* h2      = (unsigned short*)(ws + 86179840);  // 67108864 B
    float*          hmax    = (float*)(ws + 153288704);          // 8388608 B
    float*          hmin    = (float*)(ws + 161677312);          // 8388608 B
    float*          sums    = (float*)(ws + 170065920);          // 2048 B (zeroed)
    float*          ab      = (float*)(ws + 170067968);          // 2048 B
    float* sums1 = sums;        float* ab1 = ab;
    float* sums2 = sums + 128;  float* ab2 = ab + 128;
    float* sums3 = sums + 256;  float* ab3 = ab + 256;

    float* out_newxyz = (float*)d_out;            // B*NS*3 = 49152 floats
    float* out_feats  = (float*)d_out + 49152;    // B*128*NS floats

    hipMemsetAsync(sums, 0, 2048, stream);

    fps_kernel<<<NB, 256, 0, stream>>>(xyz, new_xyz, out_newxyz);
    transpose_kernel<<<dim3(NN/64, NB), 256, 0, stream>>>(features, ft);
    ballquery_kernel<<<(NB*NS)/4, 256, 0, stream>>>(xyz, new_xyz, idx);
    layer1_kernel<<<NCOL/256, 256, 0, stream>>>(xyz, new_xyz, idx, ft, W1, h1);
    stats_kernel<<<1024, 256, 0, stream>>>(h1, sums1);
    finalize_kernel<<<1, 128, 0, stream>>>(sums1, g1, b1, ab1, 64);
    layer2_kernel<<<NCOL/256, 256, 0, stream>>>(h1, ab1, W2, h2);
    stats_kernel<<<1024, 256, 0, stream>>>(h2, sums2);
    finalize_kernel<<<1, 128, 0, stream>>>(sums2, g2, b2, ab2, 64);
    layer3_kernel<<<NCOL/256, 256, 0, stream>>>(h2, ab2, W3, hmax, hmin, sums3);
    finalize_kernel<<<1, 128, 0, stream>>>(sums3, g3, b3, ab3, 128);
    final_kernel<<<(NB*128*NS)/256, 256, 0, stream>>>(hmax, hmin, ab3, out_feats);
}